// Round 11
// baseline (386.308 us; speedup 1.0000x reference)
//
#include <hip/hip_runtime.h>
#include <stdint.h>

typedef __bf16 bf16x8 __attribute__((ext_vector_type(8)));
typedef float floatx4 __attribute__((ext_vector_type(4)));
typedef unsigned short ushort_t;

__device__ __forceinline__ ushort_t bf16rne(float f) {
    union { float f; unsigned u; } v; v.f = f;
    return (ushort_t)((v.u + 0x7fffu + ((v.u >> 16) & 1u)) >> 16);
}

// async global->LDS, 16B per lane; LDS dest = base + lane*16 (wave-uniform base)
__device__ __forceinline__ void gl_lds16(const ushort_t* g, ushort_t* l) {
    __builtin_amdgcn_global_load_lds(
        (const __attribute__((address_space(1))) unsigned int*)g,
        (__attribute__((address_space(3))) unsigned int*)l, 16, 0, 0);
}

// Verified (round 4/6) tile layout: 8 segs x 1KB per 32-k, XOR swizzle.
//   Staging lane = 4*rl + cl fetches (row rl, chunk cl ^ ((rl>>1)&3)): DMA
//   fast path; frag read slot 4*ln15 + (q ^ ((ln15>>1)&3)): conflict-free.
// Round 11: pair kernel's LDS shrunk 70.7 -> 54.3 KB via union (staging lo
//   16KB | W1b/sH1 share [16,48KB); one added barrier after GEMM1 K-loop
//   legalizes the overlap) -> 3 blocks/CU (was 2). Round-10 pairing kept.

// ---------------- prep: convert x + 4 LDS-tiled weight transposes ------------
__global__ void prep(const float* __restrict__ x, ushort_t* __restrict__ x16,
                     const float* __restrict__ ew1, ushort_t* __restrict__ ew1t,
                     const float* __restrict__ ew2, ushort_t* __restrict__ ew2t,
                     const float* __restrict__ rw1, ushort_t* __restrict__ rw1t,
                     const float* __restrict__ rw2, ushort_t* __restrict__ rw2t) {
    __shared__ ushort_t sT[64 * 65];
    int b = blockIdx.x, tid = threadIdx.x;
    if (b < 16384) {
        int i = b * 256 + tid;   // 16,777,216/4 float4s
        float4 f = ((const float4*)x)[i];
        union { ushort_t s[4]; uint2 v; } pk;
        pk.s[0] = bf16rne(f.x); pk.s[1] = bf16rne(f.y);
        pk.s[2] = bf16rne(f.z); pk.s[3] = bf16rne(f.w);
        ((uint2*)x16)[i] = pk.v;
        return;
    }
    // 64x64 tile transpose: in fp32 [K][N] -> out bf16 [N][K]
    const float* in; ushort_t* outp; int K, N, k0, n0;
    int i = b - 16384;
    if (i < 160) {        // ew1 [10][512][128]
        int e = i >> 4, t = i & 15;
        in = ew1 + e * 65536; outp = ew1t + e * 65536;
        K = 512; N = 128; k0 = (t >> 1) * 64; n0 = (t & 1) * 64;
    } else if (i < 200) { // ew2 [10][128][128]
        i -= 160; int e = i >> 2, t = i & 3;
        in = ew2 + e * 16384; outp = ew2t + e * 16384;
        K = 128; N = 128; k0 = (t >> 1) * 64; n0 = (t & 1) * 64;
    } else if (i < 232) { // rw1 [512][256]
        i -= 200; in = rw1; outp = rw1t;
        K = 512; N = 256; k0 = (i >> 2) * 64; n0 = (i & 3) * 64;
    } else {              // rw2 [256][128]
        i -= 232; in = rw2; outp = rw2t;
        K = 256; N = 128; k0 = (i >> 1) * 64; n0 = (i & 1) * 64;
    }
    {
        int c = tid & 63, r0 = tid >> 6;
#pragma unroll
        for (int p = 0; p < 16; ++p) {
            int r = r0 * 16 + p;
            sT[c * 65 + r] = bf16rne(in[(size_t)(k0 + r) * N + n0 + c]);
        }
        __syncthreads();
        int rr = tid & 63, c0 = tid >> 6;
#pragma unroll
        for (int p = 0; p < 16; ++p) {
            int cc = c0 * 16 + p;
            outp[(size_t)(n0 + cc) * K + k0 + rr] = sT[cc * 65 + rr];
        }
    }
}

// --------- merged main: ids 0..255 = router blocks, 256..1535 = expert pairs
__global__ __launch_bounds__(256, 3)
void fused_main(const ushort_t* __restrict__ x16,
                const ushort_t* __restrict__ rw1t, const float* __restrict__ rb1,
                const ushort_t* __restrict__ rw2t, const float* __restrict__ rb2,
                const float* __restrict__ rw3, const float* __restrict__ rb3,
                const float* __restrict__ u,
                const ushort_t* __restrict__ ew1t, const ushort_t* __restrict__ ew2t,
                const float* __restrict__ eb1, const float* __restrict__ eb2,
                const float* __restrict__ ew3, const float* __restrict__ eb3,
                float* __restrict__ wts, float* __restrict__ chart) {
    // 48KB union (elems are ushort):
    //   GEMM1 staging: x [0,4096) | W1a [4096,8192) | W1b [8192,12288)
    //   sH1:           [8192,24576)  (W1b region reused after k-loop barrier)
    //   GEMM2 W2/rw2 staging: [0,8192)
    //   router sw3/lgbuf overlay: [0,5120)
    __shared__ alignas(16) ushort_t sU[24576];
    __shared__ float sB1[2][128];
    __shared__ float sB2[2][128];
    __shared__ float sW3e[2][256];
    __shared__ float zbuf[128][2];

    const int tid = threadIdx.x;
    const int id = blockIdx.x;
    const int wave = tid >> 6, lane = tid & 63;
    const int ln15 = lane & 15, q = lane >> 4;
    const int wm = (wave & 1) * 64, wn = (wave >> 1) * 64;
    const int mhalf = wm >> 6, nhalf = wn >> 6;
    const int rl = lane >> 2, cl = lane & 3;
    const int sw = (cl ^ ((rl >> 1) & 3)) * 8;
    const int rg0 = wave * 2, rg1 = rg0 + 1;
    const int fslot = (4 * ln15 + (q ^ ((ln15 >> 1) & 3))) * 8;

    if (id < 256) {
        // ================= router block (round-6 verified body) =================
        const int rb = (id & 7) * 32 + (id >> 3);   // XCD-aligned with expert mapping
        if (tid < 128) sB2[0][tid] = rb2[tid];
        else sB2[1][tid - 128] = rb2[tid];
        const ushort_t* xblk = x16 + (size_t)rb * 128 * 512;

        floatx4 acc2[4][4];
#pragma unroll
        for (int i = 0; i < 4; ++i)
#pragma unroll
            for (int j = 0; j < 4; ++j) acc2[i][j] = (floatx4){0.f, 0.f, 0.f, 0.f};

        for (int ph = 0; ph < 2; ++ph) {
            if (tid < 128) sB1[0][tid] = rb1[ph * 128 + tid];
            const ushort_t* w1base = rw1t + (size_t)ph * 128 * 512;

            floatx4 acc[4][4];
#pragma unroll
            for (int i = 0; i < 4; ++i)
#pragma unroll
                for (int j = 0; j < 4; ++j) acc[i][j] = (floatx4){0.f, 0.f, 0.f, 0.f};

            for (int k0 = 0; k0 < 512; k0 += 32) {
                __syncthreads();
                gl_lds16(xblk + (size_t)(rg0 * 16 + rl) * 512 + k0 + sw, &sU[rg0 * 512]);
                gl_lds16(xblk + (size_t)(rg1 * 16 + rl) * 512 + k0 + sw, &sU[rg1 * 512]);
                gl_lds16(w1base + (size_t)(rg0 * 16 + rl) * 512 + k0 + sw, &sU[4096 + rg0 * 512]);
                gl_lds16(w1base + (size_t)(rg1 * 16 + rl) * 512 + k0 + sw, &sU[4096 + rg1 * 512]);
                __syncthreads();
                bf16x8 a[4], b[4];
#pragma unroll
                for (int t = 0; t < 4; ++t) a[t] = *(const bf16x8*)(&sU[4096 + (mhalf * 4 + t) * 512 + fslot]);
#pragma unroll
                for (int t = 0; t < 4; ++t) b[t] = *(const bf16x8*)(&sU[(nhalf * 4 + t) * 512 + fslot]);
#pragma unroll
                for (int i = 0; i < 4; ++i)
#pragma unroll
                    for (int j = 0; j < 4; ++j)
                        acc[i][j] = __builtin_amdgcn_mfma_f32_16x16x32_bf16(a[i], b[j], acc[i][j], 0, 0, 0);
            }

            // epilogue -> sH1 at [8192,24576) (disjoint from router's 16KB staging)
#pragma unroll
            for (int i = 0; i < 4; ++i) {
                int hbase = wm + 16 * i;
                int kh = hbase >> 5;
                int qhi = (hbase >> 4) & 1;
                int slotq = 2 * qhi + (q >> 1);
                int h0 = hbase + q * 4;
#pragma unroll
                for (int j = 0; j < 4; ++j) {
                    union { ushort_t s[4]; uint2 v; } pk;
#pragma unroll
                    for (int r = 0; r < 4; ++r)
                        pk.s[r] = bf16rne(fmaxf(acc[i][j][r] + sB1[0][h0 + r], 0.f));
                    *(uint2*)(&sU[8192 + kh * 4096 + (nhalf * 4 + j) * 512 + slotq * 128 + ln15 * 8 + (q & 1) * 4]) = pk.v;
                }
            }

            for (int p = 0; p < 2; ++p) {
                __syncthreads();
#pragma unroll
                for (int r = 0; r < 4; ++r) {
                    int s = wave * 4 + r;
                    int khl = s >> 3, rg = s & 7;
                    int kh = p * 2 + khl;
                    gl_lds16(rw2t + (size_t)(rg * 16 + rl) * 256 + ph * 128 + kh * 32 + sw, &sU[s * 512]);
                }
                __syncthreads();
#pragma unroll
                for (int khl = 0; khl < 2; ++khl) {
                    int kh = p * 2 + khl;
                    bf16x8 a[4], b[4];
#pragma unroll
                    for (int t = 0; t < 4; ++t) a[t] = *(const bf16x8*)(&sU[(khl * 8 + mhalf * 4 + t) * 512 + fslot]);
#pragma unroll
                    for (int t = 0; t < 4; ++t) b[t] = *(const bf16x8*)(&sU[8192 + kh * 4096 + (nhalf * 4 + t) * 512 + lane * 8]);
#pragma unroll
                    for (int i = 0; i < 4; ++i)
#pragma unroll
                        for (int j = 0; j < 4; ++j)
                            acc2[i][j] = __builtin_amdgcn_mfma_f32_16x16x32_bf16(a[i], b[j], acc2[i][j], 0, 0, 0);
                }
            }
        }

        // ---- logits + gumbel softmax; sw3/lgbuf overlay [0,5120) of sU ----
        __syncthreads();   // staging reads done -> safe to overwrite
        float* sw3r = (float*)sU;                      // 1280 floats
        float* lgbuf = (float*)(&sU[2560]);            // 1280 floats
        for (int i = tid; i < 1280; i += 256) sw3r[i] = rw3[i];
        __syncthreads();

        float lg[4][10];
#pragma unroll
        for (int j = 0; j < 4; ++j)
#pragma unroll
            for (int ee = 0; ee < 10; ++ee) lg[j][ee] = 0.f;
#pragma unroll
        for (int i = 0; i < 4; ++i) {
#pragma unroll
            for (int r = 0; r < 4; ++r) {
                int n = wm + i * 16 + q * 4 + r;
                float bias = n < 128 ? sB2[0][n] : sB2[1][n - 128];
                const float* w3r = &sw3r[n * 10];
#pragma unroll
                for (int j = 0; j < 4; ++j) {
                    float val = fmaxf(acc2[i][j][r] + bias, 0.f);
#pragma unroll
                    for (int ee = 0; ee < 10; ++ee) lg[j][ee] += val * w3r[ee];
                }
            }
        }
#pragma unroll
        for (int j = 0; j < 4; ++j)
#pragma unroll
            for (int ee = 0; ee < 10; ++ee) {
                lg[j][ee] += __shfl_xor(lg[j][ee], 16, 64);
                lg[j][ee] += __shfl_xor(lg[j][ee], 32, 64);
            }
        if (wm == 0 && q == 0) {
#pragma unroll
            for (int j = 0; j < 4; ++j) {
                int row = wn + 16 * j + ln15;
#pragma unroll
                for (int ee = 0; ee < 10; ++ee) lgbuf[row * 10 + ee] = lg[j][ee];
            }
        }
        __syncthreads();
        if (wm == 64 && q == 0) {
#pragma unroll
            for (int j = 0; j < 4; ++j) {
                int row = wn + 16 * j + ln15;
#pragma unroll
                for (int ee = 0; ee < 10; ++ee) lgbuf[row * 10 + ee] += lg[j][ee];
            }
        }
        __syncthreads();
        if (tid < 128) {
            int grow = rb * 128 + tid;
            float v[10], mx = -1e30f;
#pragma unroll
            for (int ee = 0; ee < 10; ++ee) {
                float uu = u[(size_t)grow * 10 + ee];
                uu = fminf(fmaxf(uu, 1e-10f), 1.0f);
                float g = -logf(-logf(uu) + 1e-10f);
                v[ee] = (lgbuf[tid * 10 + ee] + rb3[ee] + g) * (1.0f / 3.0f);
                mx = fmaxf(mx, v[ee]);
            }
            float s = 0.f;
#pragma unroll
            for (int ee = 0; ee < 10; ++ee) { v[ee] = expf(v[ee] - mx); s += v[ee]; }
            float inv = 1.0f / s;
#pragma unroll
            for (int ee = 0; ee < 10; ++ee) wts[(size_t)grow * 10 + ee] = v[ee] * inv;
        }
    } else {
        // ================= expert-pair block: experts e0,e0+1 on one rb ==========
        const int eid = id - 256;                  // 0..1279
        const int xcd = eid & 7, local = eid >> 3; // local 0..159
        const int pr = local % 5;                  // pair index
        const int rb = xcd * 32 + local / 5;
        const int e0 = pr * 2;

        if (tid < 128) {
            sB1[0][tid] = eb1[e0 * 128 + tid];
            sB2[0][tid] = eb2[e0 * 128 + tid];
        } else {
            sB1[1][tid - 128] = eb1[(e0 + 1) * 128 + (tid - 128)];
            sB2[1][tid - 128] = eb2[(e0 + 1) * 128 + (tid - 128)];
        }
        sW3e[0][tid] = ew3[e0 * 256 + tid];
        sW3e[1][tid] = ew3[(e0 + 1) * 256 + tid];

        const ushort_t* xblk = x16 + (size_t)rb * 128 * 512;
        const ushort_t* w1a = ew1t + (size_t)e0 * 65536;
        const ushort_t* w1b = w1a + 65536;

        floatx4 accA[4][4], accB[4][4];
#pragma unroll
        for (int i = 0; i < 4; ++i)
#pragma unroll
            for (int j = 0; j < 4; ++j) {
                accA[i][j] = (floatx4){0.f, 0.f, 0.f, 0.f};
                accB[i][j] = (floatx4){0.f, 0.f, 0.f, 0.f};
            }

        // ---- GEMM1 (shared x): h1_e^T = W1_e^T · x^T for e0 and e0+1 ----
        for (int k0 = 0; k0 < 512; k0 += 32) {
            __syncthreads();
            gl_lds16(xblk + (size_t)(rg0 * 16 + rl) * 512 + k0 + sw, &sU[rg0 * 512]);
            gl_lds16(xblk + (size_t)(rg1 * 16 + rl) * 512 + k0 + sw, &sU[rg1 * 512]);
            gl_lds16(w1a + (size_t)(rg0 * 16 + rl) * 512 + k0 + sw, &sU[4096 + rg0 * 512]);
            gl_lds16(w1a + (size_t)(rg1 * 16 + rl) * 512 + k0 + sw, &sU[4096 + rg1 * 512]);
            gl_lds16(w1b + (size_t)(rg0 * 16 + rl) * 512 + k0 + sw, &sU[8192 + rg0 * 512]);
            gl_lds16(w1b + (size_t)(rg1 * 16 + rl) * 512 + k0 + sw, &sU[8192 + rg1 * 512]);
            __syncthreads();
            bf16x8 a0[4], a1[4], b[4];
#pragma unroll
            for (int t = 0; t < 4; ++t) b[t] = *(const bf16x8*)(&sU[(nhalf * 4 + t) * 512 + fslot]);
#pragma unroll
            for (int t = 0; t < 4; ++t) a0[t] = *(const bf16x8*)(&sU[4096 + (mhalf * 4 + t) * 512 + fslot]);
#pragma unroll
            for (int t = 0; t < 4; ++t) a1[t] = *(const bf16x8*)(&sU[8192 + (mhalf * 4 + t) * 512 + fslot]);
#pragma unroll
            for (int i = 0; i < 4; ++i)
#pragma unroll
                for (int j = 0; j < 4; ++j) {
                    accA[i][j] = __builtin_amdgcn_mfma_f32_16x16x32_bf16(a0[i], b[j], accA[i][j], 0, 0, 0);
                    accB[i][j] = __builtin_amdgcn_mfma_f32_16x16x32_bf16(a1[i], b[j], accB[i][j], 0, 0, 0);
                }
        }
        __syncthreads();   // W1b region [8192,12288) reads done -> sH1 may overwrite

        // ---- per expert: epilogue -> sH1, GEMM2, GEMM3, chart ----
#pragma unroll
        for (int ex = 0; ex < 2; ++ex) {
            const int e = e0 + ex;
            const ushort_t* w2 = ew2t + (size_t)e * 16384;

            // relu(+bias) -> sH1 [8192,24576) in lane-linear GEMM2 B-frag order
#pragma unroll
            for (int i = 0; i < 4; ++i) {
                int hbase = wm + 16 * i;
                int kh = hbase >> 5;
                int qhi = (hbase >> 4) & 1;
                int slotq = 2 * qhi + (q >> 1);
                int h0 = hbase + q * 4;
#pragma unroll
                for (int j = 0; j < 4; ++j) {
                    union { ushort_t s[4]; uint2 v; } pk;
#pragma unroll
                    for (int r = 0; r < 4; ++r) {
                        float av = ex == 0 ? accA[i][j][r] : accB[i][j][r];
                        pk.s[r] = bf16rne(fmaxf(av + sB1[ex][h0 + r], 0.f));
                    }
                    *(uint2*)(&sU[8192 + kh * 4096 + (nhalf * 4 + j) * 512 + slotq * 128 + ln15 * 8 + (q & 1) * 4]) = pk.v;
                }
            }

            floatx4 acc2[4][4];
#pragma unroll
            for (int i = 0; i < 4; ++i)
#pragma unroll
                for (int j = 0; j < 4; ++j) acc2[i][j] = (floatx4){0.f, 0.f, 0.f, 0.f};

            for (int p = 0; p < 2; ++p) {
                __syncthreads();   // [0,8192) free + sH1 writes visible
#pragma unroll
                for (int r = 0; r < 4; ++r) {
                    int s = wave * 4 + r;
                    int khl = s >> 3, rg = s & 7;
                    int kh = p * 2 + khl;
                    gl_lds16(w2 + (size_t)(rg * 16 + rl) * 128 + kh * 32 + sw, &sU[s * 512]);
                }
                __syncthreads();
#pragma unroll
                for (int khl = 0; khl < 2; ++khl) {
                    int kh = p * 2 + khl;
                    bf16x8 a[4], b[4];
#pragma unroll
                    for (int t = 0; t < 4; ++t) a[t] = *(const bf16x8*)(&sU[(khl * 8 + mhalf * 4 + t) * 512 + fslot]);
#pragma unroll
                    for (int t = 0; t < 4; ++t) b[t] = *(const bf16x8*)(&sU[8192 + kh * 4096 + (nhalf * 4 + t) * 512 + lane * 8]);
#pragma unroll
                    for (int i = 0; i < 4; ++i)
#pragma unroll
                        for (int j = 0; j < 4; ++j)
                            acc2[i][j] = __builtin_amdgcn_mfma_f32_16x16x32_bf16(a[i], b[j], acc2[i][j], 0, 0, 0);
                }
            }

            // GEMM3 (L=2) + cross-wave reduce + chart write
            float zc0[4] = {0.f, 0.f, 0.f, 0.f}, zc1[4] = {0.f, 0.f, 0.f, 0.f};
#pragma unroll
            for (int i = 0; i < 4; ++i) {
                int o0 = wm + i * 16 + q * 4;
#pragma unroll
                for (int r = 0; r < 4; ++r) {
                    int o = o0 + r;
                    float w3a = sW3e[ex][2 * o], w3b = sW3e[ex][2 * o + 1];
                    float bias = sB2[ex][o];
#pragma unroll
                    for (int j = 0; j < 4; ++j) {
                        float val = fmaxf(acc2[i][j][r] + bias, 0.f);
                        zc0[j] += val * w3a;
                        zc1[j] += val * w3b;
                    }
                }
            }
#pragma unroll
            for (int j = 0; j < 4; ++j) {
                zc0[j] += __shfl_xor(zc0[j], 16, 64);
                zc0[j] += __shfl_xor(zc0[j], 32, 64);
                zc1[j] += __shfl_xor(zc1[j], 16, 64);
                zc1[j] += __shfl_xor(zc1[j], 32, 64);
            }
            if (wm == 0 && q == 0) {
#pragma unroll
                for (int j = 0; j < 4; ++j) {
                    int row = wn + j * 16 + ln15;
                    zbuf[row][0] = zc0[j];
                    zbuf[row][1] = zc1[j];
                }
            }
            __syncthreads();
            if (wm == 64 && q == 0) {
#pragma unroll
                for (int j = 0; j < 4; ++j) {
                    int row = wn + j * 16 + ln15;
                    zbuf[row][0] += zc0[j];
                    zbuf[row][1] += zc1[j];
                }
            }
            __syncthreads();   // also fences sH1 reads before next epilogue's writes
            {
                int row = tid >> 1, l = tid & 1;
                int grow = rb * 128 + row;
                chart[(size_t)e * 65536 + (size_t)grow * 2 + l] = zbuf[row][l] + eb3[e * 2 + l];
            }
        }
    }
}

// ---------------- final z = sum_e weights * chart ------------------
__global__ void z_final(const float* __restrict__ w, const float* __restrict__ chart,
                        float* __restrict__ z) {
    int row = blockIdx.x * 256 + threadIdx.x;
    float z0 = 0.f, z1 = 0.f;
#pragma unroll
    for (int e = 0; e < 10; ++e) {
        float we = w[(size_t)row * 10 + e];
        float2 c = *(const float2*)(&chart[(size_t)e * 65536 + (size_t)row * 2]);
        z0 += we * c.x;
        z1 += we * c.y;
    }
    float2 o; o.x = z0; o.y = z1;
    *(float2*)(&z[(size_t)row * 2]) = o;
}

extern "C" void kernel_launch(void* const* d_in, const int* in_sizes, int n_in,
                              void* d_out, int out_size, void* d_ws, size_t ws_size,
                              hipStream_t stream) {
    const float* x = (const float*)d_in[0];
    const float* u = (const float*)d_in[1];
    const float* rw1 = (const float*)d_in[2];
    const float* rb1 = (const float*)d_in[3];
    const float* rw2 = (const float*)d_in[4];
    const float* rb2 = (const float*)d_in[5];
    const float* rw3 = (const float*)d_in[6];
    const float* rb3 = (const float*)d_in[7];
    const float* ew1 = (const float*)d_in[8];
    const float* eb1 = (const float*)d_in[9];
    const float* ew2 = (const float*)d_in[10];
    const float* eb2 = (const float*)d_in[11];
    const float* ew3 = (const float*)d_in[12];
    const float* eb3 = (const float*)d_in[13];
    float* out = (float*)d_out;
    float* z = out;                 // [32768, 2]
    float* wts = out + 65536;       // [32768, 10]
    float* chart = out + 393216;    // [10, 32768, 2]

    // workspace layout (bf16 elems), all 16B-aligned
    ushort_t* x16  = (ushort_t*)d_ws;            // 32768*512  = 16,777,216
    ushort_t* ew1t = x16 + 16777216;             // 10*128*512 =    655,360
    ushort_t* ew2t = ew1t + 655360;              // 10*128*128 =    163,840
    ushort_t* rw1t = ew2t + 163840;              // 256*512    =    131,072
    ushort_t* rw2t = rw1t + 131072;              // 128*256    =     32,768

    prep<<<16624, 256, 0, stream>>>(x, x16, ew1, ew1t, ew2, ew2t, rw1, rw1t, rw2, rw2t);

    fused_main<<<1536, 256, 0, stream>>>(x16, rw1t, rb1, rw2t, rb2, rw3, rb3, u,
                                         ew1t, ew2t, eb1, eb2, ew3, eb3,
                                         wts, chart);

    z_final<<<128, 256, 0, stream>>>(wts, chart, z);
}

// Round 12
// 210.965 us; speedup vs baseline: 1.8311x; 1.8311x over previous
//
#include <hip/hip_runtime.h>
#include <stdint.h>

typedef __bf16 bf16x8 __attribute__((ext_vector_type(8)));
typedef float floatx4 __attribute__((ext_vector_type(4)));
typedef unsigned short ushort_t;

__device__ __forceinline__ ushort_t bf16rne(float f) {
    union { float f; unsigned u; } v; v.f = f;
    return (ushort_t)((v.u + 0x7fffu + ((v.u >> 16) & 1u)) >> 16);
}

// async global->LDS, 16B per lane; LDS dest = base + lane*16 (wave-uniform base)
__device__ __forceinline__ void gl_lds16(const ushort_t* g, ushort_t* l) {
    __builtin_amdgcn_global_load_lds(
        (const __attribute__((address_space(1))) unsigned int*)g,
        (__attribute__((address_space(3))) unsigned int*)l, 16, 0, 0);
}

// Verified (round 4/6) tile layout: 8 segs x 1KB per 32-k, XOR swizzle.
//   Staging lane = 4*rl + cl fetches (row rl, chunk cl ^ ((rl>>1)&3)): DMA
//   fast path; frag read slot 4*ln15 + (q ^ ((ln15>>1)&3)): conflict-free.
// Round 12: round-11 union layout (54.3 KB -> 3 blocks/CU by LDS) with the
//   spill fixed: __launch_bounds__(256,2) — arg2=3 capped the allocator at
//   ~85 VGPRs and spilled the 128-reg pair accumulators to scratch
//   (WRITE_SIZE 33->655 MB, 272 us). (256,2) keeps 128 VGPRs; residency is
//   still 3 blocks/CU via LDS (3*54,272 = 162,816 <= 163,840).

// ---------------- prep: convert x + 4 LDS-tiled weight transposes ------------
__global__ void prep(const float* __restrict__ x, ushort_t* __restrict__ x16,
                     const float* __restrict__ ew1, ushort_t* __restrict__ ew1t,
                     const float* __restrict__ ew2, ushort_t* __restrict__ ew2t,
                     const float* __restrict__ rw1, ushort_t* __restrict__ rw1t,
                     const float* __restrict__ rw2, ushort_t* __restrict__ rw2t) {
    __shared__ ushort_t sT[64 * 65];
    int b = blockIdx.x, tid = threadIdx.x;
    if (b < 16384) {
        int i = b * 256 + tid;   // 16,777,216/4 float4s
        float4 f = ((const float4*)x)[i];
        union { ushort_t s[4]; uint2 v; } pk;
        pk.s[0] = bf16rne(f.x); pk.s[1] = bf16rne(f.y);
        pk.s[2] = bf16rne(f.z); pk.s[3] = bf16rne(f.w);
        ((uint2*)x16)[i] = pk.v;
        return;
    }
    // 64x64 tile transpose: in fp32 [K][N] -> out bf16 [N][K]
    const float* in; ushort_t* outp; int K, N, k0, n0;
    int i = b - 16384;
    if (i < 160) {        // ew1 [10][512][128]
        int e = i >> 4, t = i & 15;
        in = ew1 + e * 65536; outp = ew1t + e * 65536;
        K = 512; N = 128; k0 = (t >> 1) * 64; n0 = (t & 1) * 64;
    } else if (i < 200) { // ew2 [10][128][128]
        i -= 160; int e = i >> 2, t = i & 3;
        in = ew2 + e * 16384; outp = ew2t + e * 16384;
        K = 128; N = 128; k0 = (t >> 1) * 64; n0 = (t & 1) * 64;
    } else if (i < 232) { // rw1 [512][256]
        i -= 200; in = rw1; outp = rw1t;
        K = 512; N = 256; k0 = (i >> 2) * 64; n0 = (i & 3) * 64;
    } else {              // rw2 [256][128]
        i -= 232; in = rw2; outp = rw2t;
        K = 256; N = 128; k0 = (i >> 1) * 64; n0 = (i & 1) * 64;
    }
    {
        int c = tid & 63, r0 = tid >> 6;
#pragma unroll
        for (int p = 0; p < 16; ++p) {
            int r = r0 * 16 + p;
            sT[c * 65 + r] = bf16rne(in[(size_t)(k0 + r) * N + n0 + c]);
        }
        __syncthreads();
        int rr = tid & 63, c0 = tid >> 6;
#pragma unroll
        for (int p = 0; p < 16; ++p) {
            int cc = c0 * 16 + p;
            outp[(size_t)(n0 + cc) * K + k0 + rr] = sT[cc * 65 + rr];
        }
    }
}

// --------- merged main: ids 0..255 = router blocks, 256..1535 = expert pairs
__global__ __launch_bounds__(256, 2)
void fused_main(const ushort_t* __restrict__ x16,
                const ushort_t* __restrict__ rw1t, const float* __restrict__ rb1,
                const ushort_t* __restrict__ rw2t, const float* __restrict__ rb2,
                const float* __restrict__ rw3, const float* __restrict__ rb3,
                const float* __restrict__ u,
                const ushort_t* __restrict__ ew1t, const ushort_t* __restrict__ ew2t,
                const float* __restrict__ eb1, const float* __restrict__ eb2,
                const float* __restrict__ ew3, const float* __restrict__ eb3,
                float* __restrict__ wts, float* __restrict__ chart) {
    // 48KB union (elems are ushort):
    //   GEMM1 staging: x [0,4096) | W1a [4096,8192) | W1b [8192,12288)
    //   sH1:           [8192,24576)  (W1b region reused after k-loop barrier)
    //   GEMM2 W2/rw2 staging: [0,8192)
    //   router sw3/lgbuf overlay: [0,5120)
    __shared__ alignas(16) ushort_t sU[24576];
    __shared__ float sB1[2][128];
    __shared__ float sB2[2][128];
    __shared__ float sW3e[2][256];
    __shared__ float zbuf[128][2];

    const int tid = threadIdx.x;
    const int id = blockIdx.x;
    const int wave = tid >> 6, lane = tid & 63;
    const int ln15 = lane & 15, q = lane >> 4;
    const int wm = (wave & 1) * 64, wn = (wave >> 1) * 64;
    const int mhalf = wm >> 6, nhalf = wn >> 6;
    const int rl = lane >> 2, cl = lane & 3;
    const int sw = (cl ^ ((rl >> 1) & 3)) * 8;
    const int rg0 = wave * 2, rg1 = rg0 + 1;
    const int fslot = (4 * ln15 + (q ^ ((ln15 >> 1) & 3))) * 8;

    if (id < 256) {
        // ================= router block (round-6 verified body) =================
        const int rb = (id & 7) * 32 + (id >> 3);   // XCD-aligned with expert mapping
        if (tid < 128) sB2[0][tid] = rb2[tid];
        else sB2[1][tid - 128] = rb2[tid];
        const ushort_t* xblk = x16 + (size_t)rb * 128 * 512;

        floatx4 acc2[4][4];
#pragma unroll
        for (int i = 0; i < 4; ++i)
#pragma unroll
            for (int j = 0; j < 4; ++j) acc2[i][j] = (floatx4){0.f, 0.f, 0.f, 0.f};

        for (int ph = 0; ph < 2; ++ph) {
            if (tid < 128) sB1[0][tid] = rb1[ph * 128 + tid];
            const ushort_t* w1base = rw1t + (size_t)ph * 128 * 512;

            floatx4 acc[4][4];
#pragma unroll
            for (int i = 0; i < 4; ++i)
#pragma unroll
                for (int j = 0; j < 4; ++j) acc[i][j] = (floatx4){0.f, 0.f, 0.f, 0.f};

            for (int k0 = 0; k0 < 512; k0 += 32) {
                __syncthreads();
                gl_lds16(xblk + (size_t)(rg0 * 16 + rl) * 512 + k0 + sw, &sU[rg0 * 512]);
                gl_lds16(xblk + (size_t)(rg1 * 16 + rl) * 512 + k0 + sw, &sU[rg1 * 512]);
                gl_lds16(w1base + (size_t)(rg0 * 16 + rl) * 512 + k0 + sw, &sU[4096 + rg0 * 512]);
                gl_lds16(w1base + (size_t)(rg1 * 16 + rl) * 512 + k0 + sw, &sU[4096 + rg1 * 512]);
                __syncthreads();
                bf16x8 a[4], b[4];
#pragma unroll
                for (int t = 0; t < 4; ++t) a[t] = *(const bf16x8*)(&sU[4096 + (mhalf * 4 + t) * 512 + fslot]);
#pragma unroll
                for (int t = 0; t < 4; ++t) b[t] = *(const bf16x8*)(&sU[(nhalf * 4 + t) * 512 + fslot]);
#pragma unroll
                for (int i = 0; i < 4; ++i)
#pragma unroll
                    for (int j = 0; j < 4; ++j)
                        acc[i][j] = __builtin_amdgcn_mfma_f32_16x16x32_bf16(a[i], b[j], acc[i][j], 0, 0, 0);
            }

            // epilogue -> sH1 at [8192,24576) (disjoint from router's 16KB staging)
#pragma unroll
            for (int i = 0; i < 4; ++i) {
                int hbase = wm + 16 * i;
                int kh = hbase >> 5;
                int qhi = (hbase >> 4) & 1;
                int slotq = 2 * qhi + (q >> 1);
                int h0 = hbase + q * 4;
#pragma unroll
                for (int j = 0; j < 4; ++j) {
                    union { ushort_t s[4]; uint2 v; } pk;
#pragma unroll
                    for (int r = 0; r < 4; ++r)
                        pk.s[r] = bf16rne(fmaxf(acc[i][j][r] + sB1[0][h0 + r], 0.f));
                    *(uint2*)(&sU[8192 + kh * 4096 + (nhalf * 4 + j) * 512 + slotq * 128 + ln15 * 8 + (q & 1) * 4]) = pk.v;
                }
            }

            for (int p = 0; p < 2; ++p) {
                __syncthreads();
#pragma unroll
                for (int r = 0; r < 4; ++r) {
                    int s = wave * 4 + r;
                    int khl = s >> 3, rg = s & 7;
                    int kh = p * 2 + khl;
                    gl_lds16(rw2t + (size_t)(rg * 16 + rl) * 256 + ph * 128 + kh * 32 + sw, &sU[s * 512]);
                }
                __syncthreads();
#pragma unroll
                for (int khl = 0; khl < 2; ++khl) {
                    int kh = p * 2 + khl;
                    bf16x8 a[4], b[4];
#pragma unroll
                    for (int t = 0; t < 4; ++t) a[t] = *(const bf16x8*)(&sU[(khl * 8 + mhalf * 4 + t) * 512 + fslot]);
#pragma unroll
                    for (int t = 0; t < 4; ++t) b[t] = *(const bf16x8*)(&sU[8192 + kh * 4096 + (nhalf * 4 + t) * 512 + lane * 8]);
#pragma unroll
                    for (int i = 0; i < 4; ++i)
#pragma unroll
                        for (int j = 0; j < 4; ++j)
                            acc2[i][j] = __builtin_amdgcn_mfma_f32_16x16x32_bf16(a[i], b[j], acc2[i][j], 0, 0, 0);
                }
            }
        }

        // ---- logits + gumbel softmax; sw3/lgbuf overlay [0,5120) of sU ----
        __syncthreads();   // staging reads done -> safe to overwrite
        float* sw3r = (float*)sU;                      // 1280 floats
        float* lgbuf = (float*)(&sU[2560]);            // 1280 floats
        for (int i = tid; i < 1280; i += 256) sw3r[i] = rw3[i];
        __syncthreads();

        float lg[4][10];
#pragma unroll
        for (int j = 0; j < 4; ++j)
#pragma unroll
            for (int ee = 0; ee < 10; ++ee) lg[j][ee] = 0.f;
#pragma unroll
        for (int i = 0; i < 4; ++i) {
#pragma unroll
            for (int r = 0; r < 4; ++r) {
                int n = wm + i * 16 + q * 4 + r;
                float bias = n < 128 ? sB2[0][n] : sB2[1][n - 128];
                const float* w3r = &sw3r[n * 10];
#pragma unroll
                for (int j = 0; j < 4; ++j) {
                    float val = fmaxf(acc2[i][j][r] + bias, 0.f);
#pragma unroll
                    for (int ee = 0; ee < 10; ++ee) lg[j][ee] += val * w3r[ee];
                }
            }
        }
#pragma unroll
        for (int j = 0; j < 4; ++j)
#pragma unroll
            for (int ee = 0; ee < 10; ++ee) {
                lg[j][ee] += __shfl_xor(lg[j][ee], 16, 64);
                lg[j][ee] += __shfl_xor(lg[j][ee], 32, 64);
            }
        if (wm == 0 && q == 0) {
#pragma unroll
            for (int j = 0; j < 4; ++j) {
                int row = wn + 16 * j + ln15;
#pragma unroll
                for (int ee = 0; ee < 10; ++ee) lgbuf[row * 10 + ee] = lg[j][ee];
            }
        }
        __syncthreads();
        if (wm == 64 && q == 0) {
#pragma unroll
            for (int j = 0; j < 4; ++j) {
                int row = wn + 16 * j + ln15;
#pragma unroll
                for (int ee = 0; ee < 10; ++ee) lgbuf[row * 10 + ee] += lg[j][ee];
            }
        }
        __syncthreads();
        if (tid < 128) {
            int grow = rb * 128 + tid;
            float v[10], mx = -1e30f;
#pragma unroll
            for (int ee = 0; ee < 10; ++ee) {
                float uu = u[(size_t)grow * 10 + ee];
                uu = fminf(fmaxf(uu, 1e-10f), 1.0f);
                float g = -logf(-logf(uu) + 1e-10f);
                v[ee] = (lgbuf[tid * 10 + ee] + rb3[ee] + g) * (1.0f / 3.0f);
                mx = fmaxf(mx, v[ee]);
            }
            float s = 0.f;
#pragma unroll
            for (int ee = 0; ee < 10; ++ee) { v[ee] = expf(v[ee] - mx); s += v[ee]; }
            float inv = 1.0f / s;
#pragma unroll
            for (int ee = 0; ee < 10; ++ee) wts[(size_t)grow * 10 + ee] = v[ee] * inv;
        }
    } else {
        // ================= expert-pair block: experts e0,e0+1 on one rb ==========
        const int eid = id - 256;                  // 0..1279
        const int xcd = eid & 7, local = eid >> 3; // local 0..159
        const int pr = local % 5;                  // pair index
        const int rb = xcd * 32 + local / 5;
        const int e0 = pr * 2;

        if (tid < 128) {
            sB1[0][tid] = eb1[e0 * 128 + tid];
            sB2[0][tid] = eb2[e0 * 128 + tid];
        } else {
            sB1[1][tid - 128] = eb1[(e0 + 1) * 128 + (tid - 128)];
            sB2[1][tid - 128] = eb2[(e0 + 1) * 128 + (tid - 128)];
        }
        sW3e[0][tid] = ew3[e0 * 256 + tid];
        sW3e[1][tid] = ew3[(e0 + 1) * 256 + tid];

        const ushort_t* xblk = x16 + (size_t)rb * 128 * 512;
        const ushort_t* w1a = ew1t + (size_t)e0 * 65536;
        const ushort_t* w1b = w1a + 65536;

        floatx4 accA[4][4], accB[4][4];
#pragma unroll
        for (int i = 0; i < 4; ++i)
#pragma unroll
            for (int j = 0; j < 4; ++j) {
                accA[i][j] = (floatx4){0.f, 0.f, 0.f, 0.f};
                accB[i][j] = (floatx4){0.f, 0.f, 0.f, 0.f};
            }

        // ---- GEMM1 (shared x): h1_e^T = W1_e^T · x^T for e0 and e0+1 ----
        for (int k0 = 0; k0 < 512; k0 += 32) {
            __syncthreads();
            gl_lds16(xblk + (size_t)(rg0 * 16 + rl) * 512 + k0 + sw, &sU[rg0 * 512]);
            gl_lds16(xblk + (size_t)(rg1 * 16 + rl) * 512 + k0 + sw, &sU[rg1 * 512]);
            gl_lds16(w1a + (size_t)(rg0 * 16 + rl) * 512 + k0 + sw, &sU[4096 + rg0 * 512]);
            gl_lds16(w1a + (size_t)(rg1 * 16 + rl) * 512 + k0 + sw, &sU[4096 + rg1 * 512]);
            gl_lds16(w1b + (size_t)(rg0 * 16 + rl) * 512 + k0 + sw, &sU[8192 + rg0 * 512]);
            gl_lds16(w1b + (size_t)(rg1 * 16 + rl) * 512 + k0 + sw, &sU[8192 + rg1 * 512]);
            __syncthreads();
            bf16x8 a0[4], a1[4], b[4];
#pragma unroll
            for (int t = 0; t < 4; ++t) b[t] = *(const bf16x8*)(&sU[(nhalf * 4 + t) * 512 + fslot]);
#pragma unroll
            for (int t = 0; t < 4; ++t) a0[t] = *(const bf16x8*)(&sU[4096 + (mhalf * 4 + t) * 512 + fslot]);
#pragma unroll
            for (int t = 0; t < 4; ++t) a1[t] = *(const bf16x8*)(&sU[8192 + (mhalf * 4 + t) * 512 + fslot]);
#pragma unroll
            for (int i = 0; i < 4; ++i)
#pragma unroll
                for (int j = 0; j < 4; ++j) {
                    accA[i][j] = __builtin_amdgcn_mfma_f32_16x16x32_bf16(a0[i], b[j], accA[i][j], 0, 0, 0);
                    accB[i][j] = __builtin_amdgcn_mfma_f32_16x16x32_bf16(a1[i], b[j], accB[i][j], 0, 0, 0);
                }
        }
        __syncthreads();   // W1b region [8192,12288) reads done -> sH1 may overwrite

        // ---- per expert: epilogue -> sH1, GEMM2, GEMM3, chart ----
#pragma unroll
        for (int ex = 0; ex < 2; ++ex) {
            const int e = e0 + ex;
            const ushort_t* w2 = ew2t + (size_t)e * 16384;

            // relu(+bias) -> sH1 [8192,24576) in lane-linear GEMM2 B-frag order
#pragma unroll
            for (int i = 0; i < 4; ++i) {
                int hbase = wm + 16 * i;
                int kh = hbase >> 5;
                int qhi = (hbase >> 4) & 1;
                int slotq = 2 * qhi + (q >> 1);
                int h0 = hbase + q * 4;
#pragma unroll
                for (int j = 0; j < 4; ++j) {
                    union { ushort_t s[4]; uint2 v; } pk;
#pragma unroll
                    for (int r = 0; r < 4; ++r) {
                        float av = ex == 0 ? accA[i][j][r] : accB[i][j][r];
                        pk.s[r] = bf16rne(fmaxf(av + sB1[ex][h0 + r], 0.f));
                    }
                    *(uint2*)(&sU[8192 + kh * 4096 + (nhalf * 4 + j) * 512 + slotq * 128 + ln15 * 8 + (q & 1) * 4]) = pk.v;
                }
            }

            floatx4 acc2[4][4];
#pragma unroll
            for (int i = 0; i < 4; ++i)
#pragma unroll
                for (int j = 0; j < 4; ++j) acc2[i][j] = (floatx4){0.f, 0.f, 0.f, 0.f};

            for (int p = 0; p < 2; ++p) {
                __syncthreads();   // [0,8192) free + sH1 writes visible
#pragma unroll
                for (int r = 0; r < 4; ++r) {
                    int s = wave * 4 + r;
                    int khl = s >> 3, rg = s & 7;
                    int kh = p * 2 + khl;
                    gl_lds16(w2 + (size_t)(rg * 16 + rl) * 128 + kh * 32 + sw, &sU[s * 512]);
                }
                __syncthreads();
#pragma unroll
                for (int khl = 0; khl < 2; ++khl) {
                    int kh = p * 2 + khl;
                    bf16x8 a[4], b[4];
#pragma unroll
                    for (int t = 0; t < 4; ++t) a[t] = *(const bf16x8*)(&sU[(khl * 8 + mhalf * 4 + t) * 512 + fslot]);
#pragma unroll
                    for (int t = 0; t < 4; ++t) b[t] = *(const bf16x8*)(&sU[8192 + kh * 4096 + (nhalf * 4 + t) * 512 + lane * 8]);
#pragma unroll
                    for (int i = 0; i < 4; ++i)
#pragma unroll
                        for (int j = 0; j < 4; ++j)
                            acc2[i][j] = __builtin_amdgcn_mfma_f32_16x16x32_bf16(a[i], b[j], acc2[i][j], 0, 0, 0);
                }
            }

            // GEMM3 (L=2) + cross-wave reduce + chart write
            float zc0[4] = {0.f, 0.f, 0.f, 0.f}, zc1[4] = {0.f, 0.f, 0.f, 0.f};
#pragma unroll
            for (int i = 0; i < 4; ++i) {
                int o0 = wm + i * 16 + q * 4;
#pragma unroll
                for (int r = 0; r < 4; ++r) {
                    int o = o0 + r;
                    float w3a = sW3e[ex][2 * o], w3b = sW3e[ex][2 * o + 1];
                    float bias = sB2[ex][o];
#pragma unroll
                    for (int j = 0; j < 4; ++j) {
                        float val = fmaxf(acc2[i][j][r] + bias, 0.f);
                        zc0[j] += val * w3a;
                        zc1[j] += val * w3b;
                    }
                }
            }
#pragma unroll
            for (int j = 0; j < 4; ++j) {
                zc0[j] += __shfl_xor(zc0[j], 16, 64);
                zc0[j] += __shfl_xor(zc0[j], 32, 64);
                zc1[j] += __shfl_xor(zc1[j], 16, 64);
                zc1[j] += __shfl_xor(zc1[j], 32, 64);
            }
            if (wm == 0 && q == 0) {
#pragma unroll
                for (int j = 0; j < 4; ++j) {
                    int row = wn + j * 16 + ln15;
                    zbuf[row][0] = zc0[j];
                    zbuf[row][1] = zc1[j];
                }
            }
            __syncthreads();
            if (wm == 64 && q == 0) {
#pragma unroll
                for (int j = 0; j < 4; ++j) {
                    int row = wn + j * 16 + ln15;
                    zbuf[row][0] += zc0[j];
                    zbuf[row][1] += zc1[j];
                }
            }
            __syncthreads();   // also fences sH1 reads before next epilogue's writes
            {
                int row = tid >> 1, l = tid & 1;
                int grow = rb * 128 + row;
                chart[(size_t)e * 65536 + (size_t)grow * 2 + l] = zbuf[row][l] + eb3[e * 2 + l];
            }
        }
    }
}

// ---------------- final z = sum_e weights * chart ------------------
__global__ void z_final(const float* __restrict__ w, const float* __restrict__ chart,
                        float* __restrict__ z) {
    int row = blockIdx.x * 256 + threadIdx.x;
    float z0 = 0.f, z1 = 0.f;
#pragma unroll
    for (int e = 0; e < 10; ++e) {
        float we = w[(size_t)row * 10 + e];
        float2 c = *(const float2*)(&chart[(size_t)e * 65536 + (size_t)row * 2]);
        z0 += we * c.x;
        z1 += we * c.y;
    }
    float2 o; o.x = z0; o.y = z1;
    *(float2*)(&z[(size_t)row * 2]) = o;
}

extern "C" void kernel_launch(void* const* d_in, const int* in_sizes, int n_in,
                              void* d_out, int out_size, void* d_ws, size_t ws_size,
                              hipStream_t stream) {
    const float* x = (const float*)d_in[0];
    const float* u = (const float*)d_in[1];
    const float* rw1 = (const float*)d_in[2];
    const float* rb1 = (const float*)d_in[3];
    const float* rw2 = (const float*)d_in[4];
    const float* rb2 = (const float*)d_in[5];
    const float* rw3 = (const float*)d_in[6];
    const float* rb3 = (const float*)d_in[7];
    const float* ew1 = (const float*)d_in[8];
    const float* eb1 = (const float*)d_in[9];
    const float* ew2 = (const float*)d_in[10];
    const float* eb2 = (const float*)d_in[11];
    const float* ew3 = (const float*)d_in[12];
    const float* eb3 = (const float*)d_in[13];
    float* out = (float*)d_out;
    float* z = out;                 // [32768, 2]
    float* wts = out + 65536;       // [32768, 10]
    float* chart = out + 393216;    // [10, 32768, 2]

    // workspace layout (bf16 elems), all 16B-aligned
    ushort_t* x16  = (ushort_t*)d_ws;            // 32768*512  = 16,777,216
    ushort_t* ew1t = x16 + 16777216;             // 10*128*512 =    655,360
    ushort_t* ew2t = ew1t + 655360;              // 10*128*128 =    163,840
    ushort_t* rw1t = ew2t + 163840;              // 256*512    =    131,072
    ushort_t* rw2t = rw1t + 131072;              // 128*256    =     32,768

    prep<<<16624, 256, 0, stream>>>(x, x16, ew1, ew1t, ew2, ew2t, rw1, rw1t, rw2, rw2t);

    fused_main<<<1536, 256, 0, stream>>>(x16, rw1t, rb1, rw2t, rb2, rw3, rb3, u,
                                         ew1t, ew2t, eb1, eb2, ew3, eb3,
                                         wts, chart);

    z_final<<<128, 256, 0, stream>>>(wts, chart, z);
}